// Round 1
// baseline (1305.509 us; speedup 1.0000x reference)
//
#include <hip/hip_runtime.h>
#include <hip/hip_bf16.h>
#include <math.h>

#define B_ 64
#define N_ 1024
#define E_ 524288
#define K1_ 512
#define K2_ 256
#define K3_ 128
#define M0_ 65536
#define M1_ 32768
#define M2_ 16384
#define M3_ 8192

static __device__ __forceinline__ float eluf(float x){ return x > 0.f ? x : expm1f(x); }

__global__ void k_fill(float* __restrict__ p, float v, int n){
  int i = blockIdx.x*256 + threadIdx.x; if (i<n) p[i]=v;
}

// H[m,n] = sum_k X[m,k]*W[k,n];  N = 1<<nsh
__global__ void k_matmul(const float* __restrict__ X, const float* __restrict__ W,
                         float* __restrict__ H, int M, int K, int nsh){
  int total = M<<nsh;
  int i = blockIdx.x*256 + threadIdx.x;
  if (i>=total) return;
  int n = i & ((1<<nsh)-1);
  int m = i >> nsh;
  const float* xr = X + (size_t)m*K;
  float acc = 0.f;
  #pragma unroll 4
  for (int k=0;k<K;++k) acc = fmaf(xr[k], W[(k<<nsh)+n], acc);
  H[i] = acc;
}

__global__ void k_degedge(const int* __restrict__ dst, const float* __restrict__ ev,
                          float* __restrict__ deg, int E){
  int i = blockIdx.x*256 + threadIdx.x; if (i>=E) return;
  float w = ev ? ev[i] : 1.f;
  if (w != 0.f) atomicAdd(&deg[dst[i]], w);
}

__global__ void k_rsqrt(float* __restrict__ d, int n){
  int i = blockIdx.x*256+threadIdx.x; if (i<n) d[i] = rsqrtf(d[i]);
}

// out = b + H * 2*dinv^2   (self-loop term + bias, initializes accumulator)
__global__ void k_self(const float* __restrict__ H, const float* __restrict__ dinv,
                       const float* __restrict__ b, float* __restrict__ out, int M, int nsh){
  int total = M<<nsh;
  int i = blockIdx.x*256+threadIdx.x; if (i>=total) return;
  int f = i & ((1<<nsh)-1); int m = i>>nsh;
  float di = dinv[m];
  out[i] = fmaf(H[i], 2.f*di*di, b[f]);
}

__global__ void k_coef(const int* __restrict__ src, const int* __restrict__ dst,
                       const float* __restrict__ ev, const float* __restrict__ dinv,
                       float* __restrict__ coef, int E){
  int i = blockIdx.x*256+threadIdx.x; if (i>=E) return;
  float w = ev ? ev[i] : 1.f;
  coef[i] = w * dinv[src[i]] * dinv[dst[i]];
}

__global__ void k_edge_scatter(const int* __restrict__ src, const int* __restrict__ dst,
                               const float* __restrict__ coef, const float* __restrict__ H,
                               float* __restrict__ out, int E, int nsh){
  int total = E<<nsh;
  int i = blockIdx.x*256+threadIdx.x; if (i>=total) return;
  int e = i>>nsh; float c = coef[e];
  if (c == 0.f) return;
  int f = i & ((1<<nsh)-1);
  atomicAdd(&out[(dst[e]<<nsh)+f], H[(src[e]<<nsh)+f]*c);
}

__global__ void k_elu(float* __restrict__ x, int n){
  int i = blockIdx.x*256+threadIdx.x; if (i<n) x[i] = eluf(x[i]);
}

__global__ void k_score(const float* __restrict__ X, const float* __restrict__ p,
                        float* __restrict__ s, int M, int F){
  int i = blockIdx.x*256+threadIdx.x; if (i>=M) return;
  float dot=0.f, n2=0.f;
  const float* xr = X + (size_t)i*F;
  for (int f=0; f<F; ++f){ dot = fmaf(xr[f], p[f], dot); n2 = fmaf(p[f],p[f],n2); }
  s[i] = tanhf(dot / sqrtf(n2));
}

// block g sorts its npg scores descending (tie: lower index first), writes top-K
__global__ void k_topk(const float* __restrict__ score, int npg, int K,
                       int* __restrict__ perm, float* __restrict__ vals){
  __shared__ float ss[1024]; __shared__ int si[1024];
  int g = blockIdx.x, tid = threadIdx.x;
  ss[tid] = score[g*npg + tid]; si[tid] = tid;
  __syncthreads();
  for (int k=2;k<=npg;k<<=1){
    for (int j=k>>1;j>0;j>>=1){
      int ixj = tid ^ j;
      if (ixj > tid){
        float s1=ss[tid], s2=ss[ixj]; int i1=si[tid], i2=si[ixj];
        bool aAfterB = (s1 < s2) || (s1==s2 && i1 > i2);
        bool sw = ((tid & k)==0) ? aAfterB : !aAfterB;
        if (sw){ ss[tid]=s2; si[tid]=i2; ss[ixj]=s1; si[ixj]=i1; }
      }
      __syncthreads();
    }
  }
  if (tid < K){ perm[g*K+tid] = g*npg + si[tid]; vals[g*K+tid] = ss[tid]; }
}

__global__ void k_remap_set(const int* __restrict__ perm, int* __restrict__ remap, int n){
  int i = blockIdx.x*256+threadIdx.x; if (i<n) remap[perm[i]] = i;
}

__global__ void k_edge_remap(const int* __restrict__ srcIn, const int* __restrict__ dstIn,
                             const float* __restrict__ evIn, const int* __restrict__ remap,
                             int* __restrict__ srcOut, int* __restrict__ dstOut,
                             float* __restrict__ evOut, int E){
  int i = blockIdx.x*256+threadIdx.x; if (i>=E) return;
  float w = evIn ? evIn[i] : 1.f;
  int s = remap[srcIn[i]], d = remap[dstIn[i]];
  bool ok = (w != 0.f) && (s >= 0) && (d >= 0);
  srcOut[i] = s > 0 ? s : 0;
  dstOut[i] = d > 0 ? d : 0;
  evOut[i] = ok ? 1.f : 0.f;
}

// Xout[i,f] = elu(Xin[perm[i],f] * vals[i])
__global__ void k_pool_gather(const float* __restrict__ Xin, const int* __restrict__ perm,
                              const float* __restrict__ vals, float* __restrict__ Xout,
                              int Mout, int nsh){
  int total = Mout<<nsh;
  int i = blockIdx.x*256+threadIdx.x; if (i>=total) return;
  int m = i>>nsh; int f = i&((1<<nsh)-1);
  Xout[i] = eluf(Xin[(perm[m]<<nsh)+f] * vals[m]);
}

// cat[idx[r], f] = elu(Xd[r,f])   (left block of concat; cat pre-zeroed)
__global__ void k_scatter_rows(const float* __restrict__ Xd, const int* __restrict__ idx,
                               float* __restrict__ cat, int Md, int nsh, int catW){
  int total = Md<<nsh;
  int i = blockIdx.x*256+threadIdx.x; if (i>=total) return;
  int r = i>>nsh; int f = i&((1<<nsh)-1);
  cat[(size_t)idx[r]*catW + f] = eluf(Xd[i]);
}

// cat[r, off+f] = elu(Xs[r,f])   (right block of concat)
__global__ void k_copy_cols(const float* __restrict__ Xs, float* __restrict__ cat,
                            int Ms, int nsh, int catW, int off){
  int total = Ms<<nsh;
  int i = blockIdx.x*256+threadIdx.x; if (i>=total) return;
  int r = i>>nsh; int f = i&((1<<nsh)-1);
  cat[(size_t)r*catW + off + f] = eluf(Xs[i]);
}

// per-graph global max/mean pool over (1024,32), then MLP head + log_softmax
__global__ void k_head(const float* __restrict__ x13, const float* __restrict__ Wl,
                       const float* __restrict__ Wc, const float* __restrict__ bc,
                       float* __restrict__ out){
  __shared__ float smax[256], ssum[256];
  __shared__ float gv[64], g2[64], logit[10];
  int g = blockIdx.x, t = threadIdx.x;
  int f = t & 31, r0 = t >> 5;
  float mx = -3.4e38f, sm = 0.f;
  const float* base = x13 + (size_t)g*N_*32;
  for (int r=r0; r<N_; r+=8){ float v = base[r*32+f]; mx = fmaxf(mx,v); sm += v; }
  smax[t]=mx; ssum[t]=sm; __syncthreads();
  if (t<128){ smax[t]=fmaxf(smax[t],smax[t+128]); ssum[t]+=ssum[t+128]; } __syncthreads();
  if (t<64){ smax[t]=fmaxf(smax[t],smax[t+64]); ssum[t]+=ssum[t+64]; } __syncthreads();
  if (t<32){
    float m2 = fmaxf(smax[t],smax[t+32]); float s2 = ssum[t]+ssum[t+32];
    gv[t] = eluf(m2); gv[32+t] = eluf(s2 * (1.f/N_));
  }
  __syncthreads();
  if (t<64){
    float acc=0.f;
    #pragma unroll
    for (int i2=0;i2<64;++i2) acc = fmaf(gv[i2], Wl[i2*64+t], acc);
    g2[t] = eluf(acc);
  }
  __syncthreads();
  if (t<10){
    float acc = bc[t];
    #pragma unroll
    for (int j=0;j<64;++j) acc = fmaf(g2[j], Wc[j*10+t], acc);
    logit[t] = acc;
  }
  __syncthreads();
  if (t==0){
    float m=-3.4e38f; for (int c=0;c<10;++c) m=fmaxf(m,logit[c]);
    float s=0.f; for (int c=0;c<10;++c) s += expf(logit[c]-m);
    float lse = m + logf(s);
    for (int c=0;c<10;++c) out[g*10+c] = logit[c]-lse;
  }
}

extern "C" void kernel_launch(void* const* d_in, const int* in_sizes, int n_in,
                              void* d_out, int out_size, void* d_ws, size_t ws_size,
                              hipStream_t stream){
  const float* x  = (const float*)d_in[0];
  const float* W1 = (const float*)d_in[1];
  const float* b1 = (const float*)d_in[2];
  const float* p1 = (const float*)d_in[3];
  const float* W2 = (const float*)d_in[4];
  const float* b2 = (const float*)d_in[5];
  const float* p2 = (const float*)d_in[6];
  const float* W3 = (const float*)d_in[7];
  const float* b3 = (const float*)d_in[8];
  const float* p3 = (const float*)d_in[9];
  const float* W4 = (const float*)d_in[10];
  const float* b4 = (const float*)d_in[11];
  const float* W5 = (const float*)d_in[12];
  const float* b5 = (const float*)d_in[13];
  const float* W6 = (const float*)d_in[14];
  const float* b6 = (const float*)d_in[15];
  const float* W7 = (const float*)d_in[16];
  const float* b7 = (const float*)d_in[17];
  const float* Wl = (const float*)d_in[18];
  const float* Wc = (const float*)d_in[19];
  const float* bc = (const float*)d_in[20];
  const int* src0 = (const int*)d_in[21];
  const int* dst0 = (const int*)d_in[22];
  float* out = (float*)d_out;

  char* wsp = (char*)d_ws;
  size_t off = 0;
  auto alloc = [&](size_t bytes)->char*{
    char* p = wsp + off;
    off += (bytes + 255) & ~(size_t)255;
    return p;
  };
  float* bufA = (float*)alloc((size_t)2097152*4);   // x1 -> x13
  float* bufB = (float*)alloc((size_t)2097152*4);   // x3
  float* bufC = (float*)alloc((size_t)2097152*4);   // x5 -> x11
  float* bufD = (float*)alloc((size_t)2097152*4);   // x7 -> x9
  float* bufH = (float*)alloc((size_t)2097152*4);   // matmul temp
  float* cat  = (float*)alloc((size_t)6291456*4);   // concat buffers
  float* s1   = (float*)alloc((size_t)1048576*4);   // x2/x4/x6
  float* score= (float*)alloc((size_t)65536*4);
  float* vals = (float*)alloc((size_t)32768*4);
  int* idx2 = (int*)alloc((size_t)32768*4);
  int* idx4 = (int*)alloc((size_t)16384*4);
  int* idx6 = (int*)alloc((size_t)8192*4);
  int* remap = (int*)alloc((size_t)65536*4);
  int* src2 = (int*)alloc((size_t)E_*4); int* dst2=(int*)alloc((size_t)E_*4); float* ev2=(float*)alloc((size_t)E_*4);
  int* src4 = (int*)alloc((size_t)E_*4); int* dst4=(int*)alloc((size_t)E_*4); float* ev4=(float*)alloc((size_t)E_*4);
  int* src6 = (int*)alloc((size_t)E_*4); int* dst6=(int*)alloc((size_t)E_*4); float* ev6=(float*)alloc((size_t)E_*4);
  float* coef = (float*)alloc((size_t)E_*4);
  float* dinv0 = (float*)alloc((size_t)65536*4);
  float* dinv2 = (float*)alloc((size_t)32768*4);
  float* dinv4 = (float*)alloc((size_t)16384*4);
  float* dinv6 = (float*)alloc((size_t)8192*4);

  auto NB = [](int total){ return (total+255)/256; };

  auto gcn = [&](const float* xin, int M, int K, int nsh,
                 const float* Wm, const float* bm,
                 const int* es, const int* ed, const float* eev,
                 float* dinv, bool degDone, float* outp){
    k_matmul<<<NB(M<<nsh),256,0,stream>>>(xin, Wm, bufH, M, K, nsh);
    if (!degDone){
      k_fill<<<NB(M),256,0,stream>>>(dinv, 2.f, M);
      k_degedge<<<NB(E_),256,0,stream>>>(ed, eev, dinv, E_);
      k_rsqrt<<<NB(M),256,0,stream>>>(dinv, M);
    }
    k_self<<<NB(M<<nsh),256,0,stream>>>(bufH, dinv, bm, outp, M, nsh);
    k_coef<<<NB(E_),256,0,stream>>>(es, ed, eev, dinv, coef, E_);
    k_edge_scatter<<<NB(E_<<nsh),256,0,stream>>>(es, ed, coef, bufH, outp, E_, nsh);
    k_elu<<<NB(M<<nsh),256,0,stream>>>(outp, M<<nsh);
  };

  auto pool = [&](const float* xin, const float* pv, int npg, int Kk, int F, int nsh,
                  const int* si_, const int* di_, const float* evi,
                  int* so, int* dvo, float* evo, int* idxo, float* xo, int Mout, int Min){
    k_score<<<NB(Min),256,0,stream>>>(xin, pv, score, Min, F);
    k_topk<<<B_, npg, 0, stream>>>(score, npg, Kk, idxo, vals);
    hipMemsetAsync(remap, 0xFF, (size_t)Min*4, stream);
    k_remap_set<<<NB(Mout),256,0,stream>>>(idxo, remap, Mout);
    k_edge_remap<<<NB(E_),256,0,stream>>>(si_, di_, evi, remap, so, dvo, evo, E_);
    k_pool_gather<<<NB(Mout<<nsh),256,0,stream>>>(xin, idxo, vals, xo, Mout, nsh);
  };

  auto unpool = [&](const float* xd, int Md, int dsh, const int* idx,
                    const float* xs, int Ms, int ssh, float* catp, int catW, int offc){
    hipMemsetAsync(catp, 0, (size_t)Ms*catW*4, stream);
    k_scatter_rows<<<NB(Md<<dsh),256,0,stream>>>(xd, idx, catp, Md, dsh, catW);
    k_copy_cols<<<NB(Ms<<ssh),256,0,stream>>>(xs, catp, Ms, ssh, catW, offc);
  };

  // encoder
  gcn(x,   M0_, 128, 5, W1, b1, src0, dst0, nullptr, dinv0, false, bufA);                  // x1
  pool(bufA, p1, N_,  K1_, 32, 5, src0, dst0, nullptr, src2,dst2,ev2, idx2, s1, M1_, M0_); // x2
  gcn(s1,  M1_, 32, 6, W2, b2, src2,dst2,ev2, dinv2, false, bufB);                         // x3
  pool(bufB, p2, K1_, K2_, 64, 6, src2,dst2,ev2, src4,dst4,ev4, idx4, s1, M2_, M1_);       // x4
  gcn(s1,  M2_, 64, 7, W3, b3, src4,dst4,ev4, dinv4, false, bufC);                         // x5
  pool(bufC, p3, K2_, K3_, 128, 7, src4,dst4,ev4, src6,dst6,ev6, idx6, s1, M3_, M2_);      // x6
  gcn(s1,  M3_, 128, 8, W4, b4, src6,dst6,ev6, dinv6, false, bufD);                        // x7
  // decoder
  unpool(bufD, M3_, 8, idx6, bufC, M2_, 7, cat, 384, 256);                                 // x8
  gcn(cat, M2_, 384, 7, W5, b5, src4,dst4,ev4, dinv4, true, bufD);                         // x9
  unpool(bufD, M2_, 7, idx4, bufB, M1_, 6, cat, 192, 128);                                 // x10
  gcn(cat, M1_, 192, 6, W6, b6, src2,dst2,ev2, dinv2, true, bufC);                         // x11
  unpool(bufC, M1_, 6, idx2, bufA, M0_, 5, cat, 96, 64);                                   // x12
  gcn(cat, M0_, 96, 5, W7, b7, src0, dst0, nullptr, dinv0, true, bufA);                    // x13
  // head
  k_head<<<B_,256,0,stream>>>(bufA, Wl, Wc, bc, out);

  (void)in_sizes; (void)n_in; (void)out_size; (void)ws_size;
}